// Round 5
// baseline (304.902 us; speedup 1.0000x reference)
//
#include <hip/hip_runtime.h>
#include <hip/hip_bf16.h>
#include <cstdint>

typedef __bf16 bf16x8 __attribute__((ext_vector_type(8)));
typedef float f32x4 __attribute__((ext_vector_type(4)));

#define M_DIM 8192
#define H_DIM 1024
#define K_DIM 2048
#define NKT 32   // K tiles of 64

__device__ __forceinline__ void async_copy16(void* lds, const void* g) {
    __builtin_amdgcn_global_load_lds(
        (const __attribute__((address_space(1))) uint32_t*)g,
        (__attribute__((address_space(3))) uint32_t*)lds, 16, 0, 0);
}

__device__ __forceinline__ float fast_sigmoid(float x) {
    return __builtin_amdgcn_rcpf(1.0f + __expf(-x));
}
__device__ __forceinline__ float fast_tanh(float x) {
    float t = __expf(-2.0f * x);
    return (1.0f - t) * __builtin_amdgcn_rcpf(1.0f + t);
}

// ---- merged pack kernel: blocks [0,2048) pack A, [2048,4096) pack Bt ----
// A = bf16([x|h]) row-major [8192][2048], 16B-chunk c of row r stored at
// chunk pos (c&~7)|((c&7)^(r&7)).
// Bt[n'][k] = bf16(W^T), gate-interleaved rows: global gate col n_g=g*1024+j
// -> row n' = (j>>4)*64 + g*16 + (j&15); same chunk swizzle (n'&7 == j&7).
__global__ __launch_bounds__(256) void pack_ab(
    const float* __restrict__ x, const float* __restrict__ h,
    const float* __restrict__ Wx, const float* __restrict__ Wh,
    __bf16* __restrict__ A, __bf16* __restrict__ Bt) {
    __shared__ float tile[64 * 65];
    const int t = threadIdx.x;
    if (blockIdx.x < 2048) {
        const int ab = blockIdx.x;          // 4 batch rows per block
        #pragma unroll
        for (int i = 0; i < 4; ++i) {
            int p = t + i * 256;            // 0..1023
            int row = ab * 4 + (p >> 8);
            int c = p & 255;
            int col = c * 8;
            const float* src = (col < 1024) ? x + (size_t)row * 1024 + col
                                            : h + (size_t)row * 1024 + (col - 1024);
            float4 v0 = ((const float4*)src)[0];
            float4 v1 = ((const float4*)src)[1];
            union { __bf16 bb[8]; uint4 u; } pk;
            pk.bb[0] = (__bf16)v0.x; pk.bb[1] = (__bf16)v0.y;
            pk.bb[2] = (__bf16)v0.z; pk.bb[3] = (__bf16)v0.w;
            pk.bb[4] = (__bf16)v1.x; pk.bb[5] = (__bf16)v1.y;
            pk.bb[6] = (__bf16)v1.z; pk.bb[7] = (__bf16)v1.w;
            int sw = (c & ~7) | ((c & 7) ^ (row & 7));
            *(uint4*)(A + (size_t)row * K_DIM + sw * 8) = pk.u;
        }
    } else {
        const int b = blockIdx.x - 2048;
        const int bn = b & 63;
        const int bk = b >> 6;
        const int n0 = bn * 64, k0 = bk * 64;
        const float* W = (k0 < 1024) ? Wx + (size_t)k0 * 4096
                                     : Wh + (size_t)(k0 - 1024) * 4096;
        #pragma unroll
        for (int i = 0; i < 4; ++i) {
            int p = t + i * 256;
            int kr = p >> 4, c4 = p & 15;
            float4 v = *(const float4*)(W + (size_t)kr * 4096 + n0 + c4 * 4);
            float* dst = tile + kr * 65 + c4 * 4;
            dst[0] = v.x; dst[1] = v.y; dst[2] = v.z; dst[3] = v.w;
        }
        __syncthreads();
        #pragma unroll
        for (int i = 0; i < 2; ++i) {
            int p = t + i * 256;
            int n = p >> 3, ch = p & 7;
            int ng = n0 + n;                       // global gate-column 0..4095
            union { __bf16 bb[8]; uint4 u; } pk;
            #pragma unroll
            for (int j2 = 0; j2 < 8; ++j2)
                pk.bb[j2] = (__bf16)tile[(ch * 8 + j2) * 65 + n];
            int g = ng >> 10;
            int j = ng & 1023;
            int np = ((j >> 4) << 6) | (g << 4) | (j & 15);   // interleaved row
            int c = (k0 >> 3) + ch;
            int sw = (c & ~7) | ((c & 7) ^ (np & 7));
            *(uint4*)(Bt + (size_t)np * K_DIM + sw * 8) = pk.u;
        }
    }
}

// ============================================================================
// 256x256 tile, BK=64, 8 waves (2Mx4N). ROTATED pipeline, ONE barrier/K-tile.
// Per tile T (buf P=T&1), in program order:
//   MM0  (a0f,b0f -> acc[0..3])        [frags read post-barrier last tile]
//   RD12: a1f<-A1 jo0, ax1<-A0 jo1, b1f<-B jo1 ; all 4 STAGE units (T+1->P^1)
//   MM1  (a1f,b0f -> acc[4..7])
//   RD4:  ay1<-A1 jo1
//   MM0' (ax1,b1f -> acc[0..3])
//   lgkmcnt(0)                  [own reads of P drained -> WAR-safe for others]
//   vmcnt(0)                    [this tile's 8 stages = tile T+1 data landed;
//                                issued ~3 clusters earlier -> latency covered]
//   s_barrier                   [single fence: arrival + region-dead]
//   RD8: a0f<-A0(P^1) jo0, b0f<-B(P^1) jo0      [next tile's first frags]
//   MM1' (ay1,b1f -> acc[4..7])  [backs the post-barrier read burst]
// Every read clump has an MFMA cluster behind it in-wave -> LDS reads (2313
// cyc/CU/tile) overlap MFMA (2483 cyc/CU/tile) instead of summing.
// Stages into P^1 only touch regions whose readers drained >=1 barrier ago
// (tile T-1's per-wave lgkmcnt(0) precedes tile T-1's barrier in all waves).
// ============================================================================
__global__ __launch_bounds__(512, 2) void lstm_gemm(
    const __bf16* __restrict__ A, const __bf16* __restrict__ Bt,
    const float* __restrict__ bx, const float* __restrict__ cin,
    float* __restrict__ out) {
    __shared__ __bf16 lds[2][32768];   // 128 KiB

    const int tid = threadIdx.x;
    const int lane = tid & 63;
    const int wid = tid >> 6;
    const int wm = wid >> 2;           // 0..1  (M-wave)
    const int wn = wid & 3;            // 0..3  (N-wave)
    const int lm = lane & 15, lu = lane >> 4;

    // XCD swizzle: XCD x owns M-panels [4x..4x+3] (A window L2-resident),
    // streams the 16 N-panels (Bt deduped in LLC). FETCH 287->164MB (r2).
    const int b = blockIdx.x;
    const int xcd = b & 7, cc = b >> 3;     // cc 0..63
    const int bxc = xcd * 4 + (cc >> 4);    // 0..31  (M/256)
    const int by  = cc & 15;                // 0..15  (N'/256)
    const int bm0 = bxc * 256;
    const int nb0 = by * 256;

    // ---- staging base pointers (per thread) ----
    const int lr = tid >> 3;           // 0..63
    const int ch = tid & 7;
    const __bf16* pA = A + (size_t)(bm0 + lr) * K_DIM + ch * 8;
    const __bf16* pB = Bt + (size_t)(nb0 + ((lr >> 5) << 6) + (lr & 31)) * K_DIM + ch * 8;

#define STAGE_A(P, QM, KT) do { \
    async_copy16(&lds[P][((QM) << 13) + tid * 8],        pA + (QM) * 131072 + (KT) * 64); \
    async_copy16(&lds[P][((QM) << 13) + 4096 + tid * 8], pA + (QM) * 131072 + 262144 + (KT) * 64); \
} while (0)
#define STAGE_B(P, QN, KT) do { \
    async_copy16(&lds[P][16384 + ((QN) << 13) + tid * 8],        pB + (QN) * 65536 + (KT) * 64); \
    async_copy16(&lds[P][16384 + ((QN) << 13) + 4096 + tid * 8], pB + (QN) * 65536 + 262144 + (KT) * 64); \
} while (0)

    // swizzled k-chunk element offsets (row parity = lm&7)
    const int jo0 = ((0 + lu) ^ (lm & 7)) * 8;   // kk=0
    const int jo1 = ((4 + lu) ^ (lm & 7)) * 8;   // kk=1

    f32x4 acc[8][4];
    #pragma unroll
    for (int m0 = 0; m0 < 8; ++m0)
        #pragma unroll
        for (int n0 = 0; n0 < 4; ++n0)
            acc[m0][n0] = f32x4{0.f, 0.f, 0.f, 0.f};

    bf16x8 a0f[4], a1f[4], b0f[4];   // jo0 frags (tile-entry set)
    bf16x8 ax1[4], ay1[4], b1f[4];   // jo1 frags (within-tile set)

#define RD_A(P, MH, JO, DST) do { \
    _Pragma("unroll") \
    for (int m_ = 0; m_ < 4; ++m_) \
        DST[m_] = *(const bf16x8*)(&lds[P][((MH) << 13) + (wm * 64 + m_ * 16 + lm) * 64] + (JO)); \
} while (0)
#define RD_B(P, JO, DST) do { \
    _Pragma("unroll") \
    for (int n_ = 0; n_ < 4; ++n_) \
        DST[n_] = *(const bf16x8*)(&lds[P][16384 + ((n_ >> 1) << 13) + (wn * 32 + (n_ & 1) * 16 + lm) * 64] + (JO)); \
} while (0)
#define MM(MH, AR, BR) do { \
    __builtin_amdgcn_s_setprio(1); \
    __builtin_amdgcn_sched_barrier(0); \
    _Pragma("unroll") \
    for (int m_ = 0; m_ < 4; ++m_) \
        _Pragma("unroll") \
        for (int n_ = 0; n_ < 4; ++n_) \
            acc[(MH) * 4 + m_][n_] = __builtin_amdgcn_mfma_f32_16x16x32_bf16( \
                AR[m_], BR[n_], acc[(MH) * 4 + m_][n_], 0, 0, 0); \
    __builtin_amdgcn_sched_barrier(0); \
    __builtin_amdgcn_s_setprio(0); \
} while (0)

// ST: stage tile T+1 into P^1; RDN: pre-read next tile's jo0 frags from P^1
#define BODY(P, T, ST, RDN) do { \
    MM(0, a0f, b0f); \
    RD_A(P, 1, jo0, a1f); \
    RD_A(P, 0, jo1, ax1); \
    RD_B(P, jo1, b1f); \
    if (ST) { STAGE_A((P) ^ 1, 0, (T) + 1); STAGE_A((P) ^ 1, 1, (T) + 1); \
              STAGE_B((P) ^ 1, 0, (T) + 1); STAGE_B((P) ^ 1, 1, (T) + 1); } \
    __builtin_amdgcn_sched_barrier(0); \
    MM(1, a1f, b0f); \
    RD_A(P, 1, jo1, ay1); \
    __builtin_amdgcn_sched_barrier(0); \
    MM(0, ax1, b1f); \
    asm volatile("s_waitcnt lgkmcnt(0)" ::: "memory"); \
    __builtin_amdgcn_sched_barrier(0); \
    if (ST) { asm volatile("s_waitcnt vmcnt(0)" ::: "memory"); \
              __builtin_amdgcn_sched_barrier(0); } \
    __builtin_amdgcn_s_barrier(); \
    __builtin_amdgcn_sched_barrier(0); \
    if (RDN) { RD_A((P) ^ 1, 0, jo0, a0f); RD_B((P) ^ 1, jo0, b0f); } \
    __builtin_amdgcn_sched_barrier(0); \
    MM(1, ay1, b1f); \
} while (0)

    // ---- prologue: stage tile 0 -> buf0; arrival; pre-read its jo0 frags ----
    STAGE_A(0, 0, 0); STAGE_A(0, 1, 0); STAGE_B(0, 0, 0); STAGE_B(0, 1, 0);
    __builtin_amdgcn_sched_barrier(0);
    asm volatile("s_waitcnt vmcnt(0)" ::: "memory");
    __builtin_amdgcn_s_barrier();
    RD_A(0, 0, jo0, a0f); RD_B(0, jo0, b0f);
    __builtin_amdgcn_sched_barrier(0);

    #pragma unroll 1
    for (int it = 0; it < 15; ++it) {
        BODY(0, 2 * it,     true, true);
        BODY(1, 2 * it + 1, true, true);
    }
    BODY(0, 30, true,  true);    // stages tile 31, pre-reads its frags
    BODY(1, 31, false, false);   // nothing outstanding; plain finish

    // ---- LSTM epilogue: gate = n is lane-local ----
    const int j = (by * 4 + wn) * 16 + lm;
    const float bi  = bx[j];
    const float bff = bx[H_DIM + j];
    const float bg  = bx[2 * H_DIM + j];
    const float bo  = bx[3 * H_DIM + j];
    #pragma unroll
    for (int mf = 0; mf < 8; ++mf) {
        const int row0 = bm0 + wm * 128 + (mf >> 2) * 64 + (mf & 3) * 16 + lu * 4;
        #pragma unroll
        for (int r = 0; r < 4; ++r) {
            const size_t off = (size_t)(row0 + r) * H_DIM + j;
            const float iv = fast_sigmoid(acc[mf][0][r] + bi);
            const float fv = fast_sigmoid(acc[mf][1][r] + bff);
            const float gv = fast_tanh(acc[mf][2][r] + bg);
            const float ov = fast_sigmoid(acc[mf][3][r] + bo);
            const float cn = fv * cin[off] + iv * gv;
            out[off] = ov * fast_tanh(cn);
            out[(size_t)M_DIM * H_DIM + off] = cn;
        }
    }
#undef STAGE_A
#undef STAGE_B
#undef RD_A
#undef RD_B
#undef MM
#undef BODY
}

extern "C" void kernel_launch(void* const* d_in, const int* in_sizes, int n_in,
                              void* d_out, int out_size, void* d_ws, size_t ws_size,
                              hipStream_t stream) {
    const float* x  = (const float*)d_in[0];
    const float* h  = (const float*)d_in[1];
    const float* c  = (const float*)d_in[2];
    const float* Wx = (const float*)d_in[3];
    const float* bx = (const float*)d_in[4];
    const float* Wh = (const float*)d_in[5];
    float* out = (float*)d_out;

    __bf16* A  = (__bf16*)d_ws;                                      // 32 MB
    __bf16* Bt = (__bf16*)((char*)d_ws + (size_t)M_DIM * K_DIM * 2); // 16 MB

    pack_ab<<<4096, 256, 0, stream>>>(x, h, Wx, Wh, A, Bt);
    lstm_gemm<<<512, 512, 0, stream>>>(A, Bt, bx, c, out);
}